// Round 13
// baseline (243.105 us; speedup 1.0000x reference)
//
#include <hip/hip_runtime.h>

#define HIST_BINS 2048             // 2^11 bins: top-11 bits of monotonic key
#define HIST_BYTES (HIST_BINS * 4)
#define KEY_SHIFT 21
#define NPART 16                   // partial global histograms
#define RECALL_LO_C 0.95
#define GRID1 2048

#define TAB_N     4096             // softplus(-t) table, t in [0,16)
#define TAB_SCALE 256.0f           // TAB_N / 16
#define TAB_BYTES (TAB_N * 4)

// ---------------------------------------------------------------------------
// Init: softplus table  tab[i] = log1p(exp(-i/256)), i = 0..4095.
// Uses precise ocml log1pf/expf; runs once per launch (4096 elems, trivial).
// ---------------------------------------------------------------------------
__global__ __launch_bounds__(256) void init_table_kernel(float* __restrict__ tab)
{
    int i = blockIdx.x * 256 + threadIdx.x;
    if (i < TAB_N) {
        float t = (float)i * (1.0f / TAB_SCALE);
        tab[i] = log1pf(expf(-t));
    }
}

// ---------------------------------------------------------------------------
// Pass 1 (fused): CE partial sum (softplus via LDS table, ZERO per-element
// transcendentals — R9 ablation showed exp+log was a ~55us trans-pipe floor),
// positive count, and LDS-privatized 2^11-bin packed histogram.
// LDS: 16KB table + 8KB hist = 24KB -> 6 blocks/CU.
// ---------------------------------------------------------------------------
__global__ __launch_bounds__(256) void pass1_kernel(
    const float* __restrict__ pred, const int* __restrict__ tgt,
    const float* __restrict__ gtab, unsigned int* __restrict__ ghist,
    double* __restrict__ ce_sum, unsigned int* __restrict__ pos_cnt, int n)
{
    __shared__ float        stab[TAB_N];        // 16 KB
    __shared__ unsigned int lhist[HIST_BINS];   // 8 KB

    // copy softplus table to LDS (uint4-vectorized) + zero histogram
    {
        const uint4* g4 = (const uint4*)gtab;
        uint4*       s4 = (uint4*)stab;
        for (int i = threadIdx.x; i < TAB_N / 4; i += 256) s4[i] = g4[i];
        uint4* lh4 = (uint4*)lhist;
        for (int b = threadIdx.x; b < HIST_BINS / 4; b += 256)
            lh4[b] = make_uint4(0u, 0u, 0u, 0u);
    }
    __syncthreads();

    float ce = 0.0f;
    unsigned int pc = 0;

    const int tid    = blockIdx.x * blockDim.x + threadIdx.x;
    const int stride = gridDim.x * blockDim.x;
    const int n4     = n >> 2;

    const float4* p4 = (const float4*)pred;
    const int4*   t4 = (const int4*)tgt;

    for (int i = tid; i < n4; i += stride) {
        float4 x = p4[i];
        int4   t = t4[i];
        float xs[4] = {x.x, x.y, x.z, x.w};
        int   ts[4] = {t.x, t.y, t.z, t.w};
#pragma unroll
        for (int c = 0; c < 4; ++c) {
            float xv = xs[c];
            // linear part: max(x,0) - x*t   (exact, VALU)
            ce += fmaxf(xv, 0.0f) - xv * (float)ts[c];
            // softplus(-|x|) via table + linear interp (err ~5e-7)
            float a = fabsf(xv);
            float s = fminf(a * TAB_SCALE, (float)(TAB_N - 2));
            int   k = (int)s;
            float f = s - (float)k;
            float v0 = stab[k];
            float v1 = stab[k + 1];
            ce += v0 + f * (v1 - v0);
            pc += (unsigned int)ts[c];
            // histogram on monotonic key
            unsigned int u = __float_as_uint(xv);
            int          m = (int)u >> 31;
            unsigned int key = u ^ (0x80000000u | (unsigned int)m);
            atomicAdd(&lhist[key >> KEY_SHIFT], ts[c] ? 65536u : 1u);
        }
    }
    // scalar tail for n % 4 (none for N = 8.4M)
    for (int i = (n4 << 2) + tid; i < n; i += stride) {
        float xv = pred[i];
        int   ti = tgt[i];
        ce += fmaxf(xv, 0.0f) - xv * (float)ti;
        float a = fabsf(xv);
        float s = fminf(a * TAB_SCALE, (float)(TAB_N - 2));
        int   k = (int)s;
        float f = s - (float)k;
        ce += stab[k] + f * (stab[k + 1] - stab[k]);
        pc += (unsigned int)ti;
        unsigned int u = __float_as_uint(xv);
        int          m = (int)u >> 31;
        unsigned int key = u ^ (0x80000000u | (unsigned int)m);
        atomicAdd(&lhist[key >> KEY_SHIFT], ti ? 65536u : 1u);
    }

    // CE / pos-count: wave reduce, one atomic per wave
    for (int off = 32; off > 0; off >>= 1) {
        ce += __shfl_down(ce, off);
        pc += __shfl_down(pc, off);
    }
    if ((threadIdx.x & 63) == 0) {
        atomicAdd(ce_sum, (double)ce);
        atomicAdd(pos_cnt, pc);
    }

    // flush LDS histogram into this block's partial (rotated start)
    __syncthreads();
    unsigned int* gp = ghist + (blockIdx.x & (NPART - 1)) * HIST_BINS;
    const int nq  = HIST_BINS / 4;                 // 512
    const int rot = (blockIdx.x * 32) & (nq - 1);
    uint4* lh4 = (uint4*)lhist;
    for (int i = threadIdx.x; i < nq; i += 256) {
        int b = (i + rot) & (nq - 1);
        uint4 v = lh4[b];
        if (v.x) atomicAdd(&gp[4 * b + 0], v.x);
        if (v.y) atomicAdd(&gp[4 * b + 1], v.y);
        if (v.z) atomicAdd(&gp[4 * b + 2], v.z);
        if (v.w) atomicAdd(&gp[4 * b + 3], v.w);
    }
}

// ---------------------------------------------------------------------------
// Pass 2 (single block, 256 threads): each thread owns an 8-bin chunk; sums
// the NPART partials UNPACKED, Hillis-Steele scan for the descending positive
// prefix, then the bin-wise pAUC sum:
//   contribution = ng * E_f~U(0,1)[ max(0, (CP - 0.95P) + p*f) ]
// pAUC = S/(P*Ng);  loss = 0.5*CE_mean + 0.5*(1 - clip(pAUC/0.1,0,1)^2)
// ---------------------------------------------------------------------------
__global__ __launch_bounds__(256) void pass2_kernel(
    const unsigned int* __restrict__ hist, const double* __restrict__ ce_sum,
    const unsigned int* __restrict__ pos_cnt, float* __restrict__ out, int n)
{
    __shared__ double chunk_pos[256];
    __shared__ double sred[256];

    const int tid = threadIdx.x;
    const int lo  = HIST_BINS - (tid + 1) * 8;    // thread's 8-bin chunk

    unsigned int pos[8] = {0,0,0,0,0,0,0,0};
    unsigned int neg[8] = {0,0,0,0,0,0,0,0};
    const uint4* h4 = (const uint4*)hist;
#pragma unroll
    for (int p = 0; p < NPART; ++p) {
#pragma unroll
        for (int j = 0; j < 2; ++j) {
            uint4 v = h4[p * (HIST_BINS / 4) + lo / 4 + j];
            pos[4*j+0] += v.x >> 16;  neg[4*j+0] += v.x & 0xFFFFu;
            pos[4*j+1] += v.y >> 16;  neg[4*j+1] += v.y & 0xFFFFu;
            pos[4*j+2] += v.z >> 16;  neg[4*j+2] += v.z & 0xFFFFu;
            pos[4*j+3] += v.w >> 16;  neg[4*j+3] += v.w & 0xFFFFu;
        }
    }

    double psum = 0.0;
#pragma unroll
    for (int i = 0; i < 8; ++i) psum += (double)pos[i];
    chunk_pos[tid] = psum;
    __syncthreads();

    double v = psum;
    for (int s = 1; s < 256; s <<= 1) {
        double add = (tid >= s) ? chunk_pos[tid - s] : 0.0;
        __syncthreads();
        v += add;
        chunk_pos[tid] = v;
        __syncthreads();
    }
    double CP = v - psum;   // positives strictly above this chunk

    const unsigned int P = *pos_cnt;
    const double T = RECALL_LO_C * (double)P;

    double S = 0.0;
#pragma unroll
    for (int i = 7; i >= 0; --i) {
        double p  = (double)pos[i];
        double ng = (double)neg[i];
        if (ng > 0.0) {
            double a = CP - T;
            double contrib;
            if (a >= 0.0) {
                contrib = a + 0.5 * p;
            } else {
                double ac = a + p;
                contrib = (ac > 0.0 && p > 0.0) ? (ac * ac) / (2.0 * p) : 0.0;
            }
            S += ng * contrib;
        }
        CP += p;
    }
    sred[tid] = S;
    __syncthreads();
    for (int s = 128; s > 0; s >>= 1) {
        if (tid < s) sred[tid] += sred[tid + s];
        __syncthreads();
    }

    if (tid == 0) {
        double Ng = (double)n - (double)P;
        double pauc = 0.0;
        if (P > 0 && Ng > 0.0) pauc = sred[0] / ((double)P * Ng);
        double avg = pauc / (2.0 * (1.0 - RECALL_LO_C));   // pauc / 0.1
        avg = fmin(fmax(avg, 0.0), 1.0);
        double ce = *ce_sum / (double)n;
        out[0] = (float)(0.5 * ce + 0.5 * (1.0 - avg * avg));
    }
}

extern "C" void kernel_launch(void* const* d_in, const int* in_sizes, int n_in,
                              void* d_out, int out_size, void* d_ws, size_t ws_size,
                              hipStream_t stream)
{
    const float* pred = (const float*)d_in[0];
    const int*   tgt  = (const int*)d_in[1];
    const int n = in_sizes[0];  // predictions is (N,1) -> N elements

    char* ws = (char*)d_ws;
    unsigned int* ghist   = (unsigned int*)ws;                       // NPART x 8KB = 128KB
    double*       ce_sum  = (double*)(ws + NPART * HIST_BYTES);      // 8B
    unsigned int* pos_cnt = (unsigned int*)(ws + NPART * HIST_BYTES + 8);
    float*        gtab    = (float*)(ws + NPART * HIST_BYTES + 16);  // 16KB, 16B-aligned

    hipMemsetAsync(d_ws, 0, NPART * HIST_BYTES + 16, stream);

    init_table_kernel<<<TAB_N / 256, 256, 0, stream>>>(gtab);
    pass1_kernel<<<GRID1, 256, 0, stream>>>(pred, tgt, gtab, ghist, ce_sum, pos_cnt, n);
    pass2_kernel<<<1, 256, 0, stream>>>(ghist, ce_sum, pos_cnt, (float*)d_out, n);
}

// Round 14
// 213.300 us; speedup vs baseline: 1.1397x; 1.1397x over previous
//
#include <hip/hip_runtime.h>

#define HIST_BINS 2048             // 2^11 bins: top-11 bits of monotonic key
#define HIST_BYTES (HIST_BINS * 4)
#define KEY_SHIFT 21
#define NPART 16                   // partial global histograms
#define RECALL_LO_C 0.95
#define GRID1 2048

// ---------------------------------------------------------------------------
// Pure-VALU softplus(-a) = log1p(exp(-a)), a >= 0. No trans pipe, no LDS.
//   t = a*log2e, clamp 30 (tail < 1e-9); i = rint(t), r = t-i in [-.5,.5]
//   m = 2^(-r) via Cephes exp2 poly; y = m * 2^(-i) via exponent bit-sub
//   log(1+y): z in (1,2], sqrt2 reduction, Cephes logf poly
// ---------------------------------------------------------------------------
__device__ __forceinline__ float softplus_neg(float a)
{
    const float LOG2E = 1.44269504088896341f;
    float t = fminf(a * LOG2E, 30.0f);
    float fi = rintf(t);
    float x = fi - t;                     // x = -r in [-0.5, 0.5]
    // 2^x, Cephes exp2f poly
    float p = 1.535336188319500e-4f;
    p = p * x + 1.339887440266574e-3f;
    p = p * x + 9.618437357674640e-3f;
    p = p * x + 5.550332471162809e-2f;
    p = p * x + 2.402264791363012e-1f;
    p = p * x + 6.931472028550421e-1f;
    float m = p * x + 1.0f;               // 2^(-r) in [0.7071, 1.4143]
    int ii = (int)fi;                     // 0..30
    float y = __uint_as_float(__float_as_uint(m) - ((unsigned int)ii << 23));
    // log(1 + y), y in (0, 1]
    float z1 = 1.0f + y;                  // (1, 2]
    bool red = z1 > 1.41421356f;
    float zr = red ? z1 * 0.5f : z1;
    float el = red ? 0.69314718056f : 0.0f;
    float w  = zr - 1.0f;                 // (-0.293, 0.414]
    float zz = w * w;
    float q = 7.0376836292e-2f;
    q = q * w - 1.1514610310e-1f;
    q = q * w + 1.1676998740e-1f;
    q = q * w - 1.2420140846e-1f;
    q = q * w + 1.4249322787e-1f;
    q = q * w - 1.6668057665e-1f;
    q = q * w + 2.0000714765e-1f;
    q = q * w - 2.4999993993e-1f;
    q = q * w + 3.3333331174e-1f;
    return w + (w * zz * q - 0.5f * zz) + el;
}

// ---------------------------------------------------------------------------
// Pass 1 (fused): CE partial sum (pure-VALU softplus — R13 showed LDS-table
// gather mixed with LDS atomics is a 3.4x regression; R9 showed trans ops are
// a ~55us floor), positive count, LDS-privatized 2^11-bin packed histogram
// ([pos<<16 | neg], 8 KB LDS). NPART-partial rotated flush.
// ---------------------------------------------------------------------------
__global__ __launch_bounds__(256) void pass1_kernel(
    const float* __restrict__ pred, const int* __restrict__ tgt,
    unsigned int* __restrict__ ghist, double* __restrict__ ce_sum,
    unsigned int* __restrict__ pos_cnt, int n)
{
    __shared__ unsigned int lhist[HIST_BINS];   // 8 KB

    uint4* lh4 = (uint4*)lhist;
    for (int b = threadIdx.x; b < HIST_BINS / 4; b += 256)
        lh4[b] = make_uint4(0u, 0u, 0u, 0u);
    __syncthreads();

    float ce = 0.0f;
    unsigned int pc = 0;

    const int tid    = blockIdx.x * blockDim.x + threadIdx.x;
    const int stride = gridDim.x * blockDim.x;
    const int n4     = n >> 2;

    const float4* p4 = (const float4*)pred;
    const int4*   t4 = (const int4*)tgt;

    for (int i = tid; i < n4; i += stride) {
        float4 x = p4[i];
        int4   t = t4[i];
        float xs[4] = {x.x, x.y, x.z, x.w};
        int   ts[4] = {t.x, t.y, t.z, t.w};
#pragma unroll
        for (int c = 0; c < 4; ++c) {
            float xv = xs[c];
            ce += fmaxf(xv, 0.0f) - xv * (float)ts[c] + softplus_neg(fabsf(xv));
            pc += (unsigned int)ts[c];
            unsigned int u = __float_as_uint(xv);
            int          m = (int)u >> 31;
            unsigned int key = u ^ (0x80000000u | (unsigned int)m);
            atomicAdd(&lhist[key >> KEY_SHIFT], ts[c] ? 65536u : 1u);
        }
    }
    // scalar tail for n % 4 (none for N = 8.4M)
    for (int i = (n4 << 2) + tid; i < n; i += stride) {
        float xv = pred[i];
        int   ti = tgt[i];
        ce += fmaxf(xv, 0.0f) - xv * (float)ti + softplus_neg(fabsf(xv));
        pc += (unsigned int)ti;
        unsigned int u = __float_as_uint(xv);
        int          m = (int)u >> 31;
        unsigned int key = u ^ (0x80000000u | (unsigned int)m);
        atomicAdd(&lhist[key >> KEY_SHIFT], ti ? 65536u : 1u);
    }

    // CE / pos-count: wave reduce, one atomic per wave
    for (int off = 32; off > 0; off >>= 1) {
        ce += __shfl_down(ce, off);
        pc += __shfl_down(pc, off);
    }
    if ((threadIdx.x & 63) == 0) {
        atomicAdd(ce_sum, (double)ce);
        atomicAdd(pos_cnt, pc);
    }

    // flush LDS histogram into this block's partial (rotated start)
    __syncthreads();
    unsigned int* gp = ghist + (blockIdx.x & (NPART - 1)) * HIST_BINS;
    const int nq  = HIST_BINS / 4;                 // 512
    const int rot = (blockIdx.x * 32) & (nq - 1);
    for (int i = threadIdx.x; i < nq; i += 256) {
        int b = (i + rot) & (nq - 1);
        uint4 v = lh4[b];
        if (v.x) atomicAdd(&gp[4 * b + 0], v.x);
        if (v.y) atomicAdd(&gp[4 * b + 1], v.y);
        if (v.z) atomicAdd(&gp[4 * b + 2], v.z);
        if (v.w) atomicAdd(&gp[4 * b + 3], v.w);
    }
}

// ---------------------------------------------------------------------------
// Pass 2 (single block, 256 threads): each thread owns an 8-bin chunk; sums
// the NPART partials UNPACKED, Hillis-Steele scan for the descending positive
// prefix, then the bin-wise pAUC sum:
//   contribution = ng * E_f~U(0,1)[ max(0, (CP - 0.95P) + p*f) ]
// pAUC = S/(P*Ng);  loss = 0.5*CE_mean + 0.5*(1 - clip(pAUC/0.1,0,1)^2)
// ---------------------------------------------------------------------------
__global__ __launch_bounds__(256) void pass2_kernel(
    const unsigned int* __restrict__ hist, const double* __restrict__ ce_sum,
    const unsigned int* __restrict__ pos_cnt, float* __restrict__ out, int n)
{
    __shared__ double chunk_pos[256];
    __shared__ double sred[256];

    const int tid = threadIdx.x;
    const int lo  = HIST_BINS - (tid + 1) * 8;    // thread's 8-bin chunk

    unsigned int pos[8] = {0,0,0,0,0,0,0,0};
    unsigned int neg[8] = {0,0,0,0,0,0,0,0};
    const uint4* h4 = (const uint4*)hist;
#pragma unroll
    for (int p = 0; p < NPART; ++p) {
#pragma unroll
        for (int j = 0; j < 2; ++j) {
            uint4 v = h4[p * (HIST_BINS / 4) + lo / 4 + j];
            pos[4*j+0] += v.x >> 16;  neg[4*j+0] += v.x & 0xFFFFu;
            pos[4*j+1] += v.y >> 16;  neg[4*j+1] += v.y & 0xFFFFu;
            pos[4*j+2] += v.z >> 16;  neg[4*j+2] += v.z & 0xFFFFu;
            pos[4*j+3] += v.w >> 16;  neg[4*j+3] += v.w & 0xFFFFu;
        }
    }

    double psum = 0.0;
#pragma unroll
    for (int i = 0; i < 8; ++i) psum += (double)pos[i];
    chunk_pos[tid] = psum;
    __syncthreads();

    double v = psum;
    for (int s = 1; s < 256; s <<= 1) {
        double add = (tid >= s) ? chunk_pos[tid - s] : 0.0;
        __syncthreads();
        v += add;
        chunk_pos[tid] = v;
        __syncthreads();
    }
    double CP = v - psum;   // positives strictly above this chunk

    const unsigned int P = *pos_cnt;
    const double T = RECALL_LO_C * (double)P;

    double S = 0.0;
#pragma unroll
    for (int i = 7; i >= 0; --i) {
        double p  = (double)pos[i];
        double ng = (double)neg[i];
        if (ng > 0.0) {
            double a = CP - T;
            double contrib;
            if (a >= 0.0) {
                contrib = a + 0.5 * p;
            } else {
                double ac = a + p;
                contrib = (ac > 0.0 && p > 0.0) ? (ac * ac) / (2.0 * p) : 0.0;
            }
            S += ng * contrib;
        }
        CP += p;
    }
    sred[tid] = S;
    __syncthreads();
    for (int s = 128; s > 0; s >>= 1) {
        if (tid < s) sred[tid] += sred[tid + s];
        __syncthreads();
    }

    if (tid == 0) {
        double Ng = (double)n - (double)P;
        double pauc = 0.0;
        if (P > 0 && Ng > 0.0) pauc = sred[0] / ((double)P * Ng);
        double avg = pauc / (2.0 * (1.0 - RECALL_LO_C));   // pauc / 0.1
        avg = fmin(fmax(avg, 0.0), 1.0);
        double ce = *ce_sum / (double)n;
        out[0] = (float)(0.5 * ce + 0.5 * (1.0 - avg * avg));
    }
}

extern "C" void kernel_launch(void* const* d_in, const int* in_sizes, int n_in,
                              void* d_out, int out_size, void* d_ws, size_t ws_size,
                              hipStream_t stream)
{
    const float* pred = (const float*)d_in[0];
    const int*   tgt  = (const int*)d_in[1];
    const int n = in_sizes[0];  // predictions is (N,1) -> N elements

    char* ws = (char*)d_ws;
    unsigned int* ghist   = (unsigned int*)ws;                       // NPART x 8KB = 128KB
    double*       ce_sum  = (double*)(ws + NPART * HIST_BYTES);      // 8B
    unsigned int* pos_cnt = (unsigned int*)(ws + NPART * HIST_BYTES + 8);

    hipMemsetAsync(d_ws, 0, NPART * HIST_BYTES + 16, stream);

    pass1_kernel<<<GRID1, 256, 0, stream>>>(pred, tgt, ghist, ce_sum, pos_cnt, n);
    pass2_kernel<<<1, 256, 0, stream>>>(ghist, ce_sum, pos_cnt, (float*)d_out, n);
}

// Round 15
// 34.969 us; speedup vs baseline: 6.9521x; 6.0998x over previous
//
#include <hip/hip_runtime.h>

#define HIST_BINS 2048             // 2^11 bins: top-11 bits of monotonic key
#define HIST_BYTES (HIST_BINS * 4)
#define KEY_SHIFT 21
#define NPART 16                   // partial global histograms
#define RECALL_LO_C 0.95
#define GRID1 2048

// ---------------------------------------------------------------------------
// Pure-VALU softplus(-a) = log1p(exp(-a)), a >= 0. No trans pipe, no LDS.
// ---------------------------------------------------------------------------
__device__ __forceinline__ float softplus_neg(float a)
{
    const float LOG2E = 1.44269504088896341f;
    float t = fminf(a * LOG2E, 30.0f);
    float fi = rintf(t);
    float x = fi - t;                     // in [-0.5, 0.5]
    float p = 1.535336188319500e-4f;
    p = p * x + 1.339887440266574e-3f;
    p = p * x + 9.618437357674640e-3f;
    p = p * x + 5.550332471162809e-2f;
    p = p * x + 2.402264791363012e-1f;
    p = p * x + 6.931472028550421e-1f;
    float m = p * x + 1.0f;               // 2^(-r)
    int ii = (int)fi;
    float y = __uint_as_float(__float_as_uint(m) - ((unsigned int)ii << 23));
    float z1 = 1.0f + y;                  // (1, 2]
    bool red = z1 > 1.41421356f;
    float zr = red ? z1 * 0.5f : z1;
    float el = red ? 0.69314718056f : 0.0f;
    float w  = zr - 1.0f;
    float zz = w * w;
    float q = 7.0376836292e-2f;
    q = q * w - 1.1514610310e-1f;
    q = q * w + 1.1676998740e-1f;
    q = q * w - 1.2420140846e-1f;
    q = q * w + 1.4249322787e-1f;
    q = q * w - 1.6668057665e-1f;
    q = q * w + 2.0000714765e-1f;
    q = q * w - 2.4999993993e-1f;
    q = q * w + 3.3333331174e-1f;
    return w + (w * zz * q - 0.5f * zz) + el;
}

// ---------------------------------------------------------------------------
// Pass 1: CE + pos-count reduced per block and written to PER-BLOCK SLOTS
// (no same-address atomic chains — R14 post-mortem: the serialized
// ce_sum/pos_cnt atomic chain at ~27ns/add was the real floor since R5),
// plus LDS-privatized 2^11-bin packed histogram with NPART-partial flush.
// ---------------------------------------------------------------------------
__global__ __launch_bounds__(256) void pass1_kernel(
    const float* __restrict__ pred, const int* __restrict__ tgt,
    unsigned int* __restrict__ ghist, double* __restrict__ ce_part,
    unsigned int* __restrict__ pos_part, int n)
{
    __shared__ unsigned int lhist[HIST_BINS];   // 8 KB

    uint4* lh4 = (uint4*)lhist;
    for (int b = threadIdx.x; b < HIST_BINS / 4; b += 256)
        lh4[b] = make_uint4(0u, 0u, 0u, 0u);
    __syncthreads();

    float ce = 0.0f;
    unsigned int pc = 0;

    const int tid    = blockIdx.x * blockDim.x + threadIdx.x;
    const int stride = gridDim.x * blockDim.x;
    const int n4     = n >> 2;

    const float4* p4 = (const float4*)pred;
    const int4*   t4 = (const int4*)tgt;

    for (int i = tid; i < n4; i += stride) {
        float4 x = p4[i];
        int4   t = t4[i];
        float xs[4] = {x.x, x.y, x.z, x.w};
        int   ts[4] = {t.x, t.y, t.z, t.w};
#pragma unroll
        for (int c = 0; c < 4; ++c) {
            float xv = xs[c];
            ce += fmaxf(xv, 0.0f) - xv * (float)ts[c] + softplus_neg(fabsf(xv));
            pc += (unsigned int)ts[c];
            unsigned int u = __float_as_uint(xv);
            int          m = (int)u >> 31;
            unsigned int key = u ^ (0x80000000u | (unsigned int)m);
            atomicAdd(&lhist[key >> KEY_SHIFT], ts[c] ? 65536u : 1u);
        }
    }
    // scalar tail for n % 4 (none for N = 8.4M)
    for (int i = (n4 << 2) + tid; i < n; i += stride) {
        float xv = pred[i];
        int   ti = tgt[i];
        ce += fmaxf(xv, 0.0f) - xv * (float)ti + softplus_neg(fabsf(xv));
        pc += (unsigned int)ti;
        unsigned int u = __float_as_uint(xv);
        int          m = (int)u >> 31;
        unsigned int key = u ^ (0x80000000u | (unsigned int)m);
        atomicAdd(&lhist[key >> KEY_SHIFT], ti ? 65536u : 1u);
    }

    // CE / pos-count: wave reduce -> LDS -> ONE PLAIN STORE per block
    for (int off = 32; off > 0; off >>= 1) {
        ce += __shfl_down(ce, off);
        pc += __shfl_down(pc, off);
    }
    __shared__ float        lce[4];
    __shared__ unsigned int lpc[4];
    if ((threadIdx.x & 63) == 0) {
        lce[threadIdx.x >> 6] = ce;
        lpc[threadIdx.x >> 6] = pc;
    }
    __syncthreads();
    if (threadIdx.x == 0) {
        ce_part[blockIdx.x]  = (double)(lce[0] + lce[1] + lce[2] + lce[3]);
        pos_part[blockIdx.x] = lpc[0] + lpc[1] + lpc[2] + lpc[3];
    }

    // flush LDS histogram into this block's partial (rotated start)
    for (int i = threadIdx.x; i < HIST_BINS / 4; i += 256) {
        unsigned int* gp = ghist + (blockIdx.x & (NPART - 1)) * HIST_BINS;
        const int nq  = HIST_BINS / 4;                 // 512
        const int rot = (blockIdx.x * 32) & (nq - 1);
        int b = (i + rot) & (nq - 1);
        uint4 v = lh4[b];
        if (v.x) atomicAdd(&gp[4 * b + 0], v.x);
        if (v.y) atomicAdd(&gp[4 * b + 1], v.y);
        if (v.z) atomicAdd(&gp[4 * b + 2], v.z);
        if (v.w) atomicAdd(&gp[4 * b + 3], v.w);
    }
}

// ---------------------------------------------------------------------------
// Pass 2 (single block, 256 threads):
//   phase 0: reduce per-block ce/pos partials (plain reads, no atomics)
//   phase 1-3: unpacked NPART-partial histogram sum, Hillis-Steele scan,
//   bin-wise pAUC:  contrib = ng * E_f~U(0,1)[ max(0, (CP - 0.95P) + p*f) ]
// pAUC = S/(P*Ng);  loss = 0.5*CE_mean + 0.5*(1 - clip(pAUC/0.1,0,1)^2)
// ---------------------------------------------------------------------------
__global__ __launch_bounds__(256) void pass2_kernel(
    const unsigned int* __restrict__ hist, const double* __restrict__ ce_part,
    const unsigned int* __restrict__ pos_part, float* __restrict__ out, int n)
{
    __shared__ double sA[256];
    __shared__ double sB[256];

    const int tid = threadIdx.x;

    // phase 0: totals from per-block partials
    double ce_acc = 0.0, p_acc = 0.0;
    for (int i = tid; i < GRID1; i += 256) {
        ce_acc += ce_part[i];
        p_acc  += (double)pos_part[i];
    }
    sA[tid] = ce_acc;
    sB[tid] = p_acc;
    __syncthreads();
    for (int s = 128; s > 0; s >>= 1) {
        if (tid < s) { sA[tid] += sA[tid + s]; sB[tid] += sB[tid + s]; }
        __syncthreads();
    }
    const double CE_total = sA[0];
    const double Pd       = sB[0];
    __syncthreads();

    // phase 1: unpacked histogram chunk (8 bins/thread) across NPART partials
    const int lo = HIST_BINS - (tid + 1) * 8;
    unsigned int pos[8] = {0,0,0,0,0,0,0,0};
    unsigned int neg[8] = {0,0,0,0,0,0,0,0};
    const uint4* h4 = (const uint4*)hist;
#pragma unroll
    for (int p = 0; p < NPART; ++p) {
#pragma unroll
        for (int j = 0; j < 2; ++j) {
            uint4 v = h4[p * (HIST_BINS / 4) + lo / 4 + j];
            pos[4*j+0] += v.x >> 16;  neg[4*j+0] += v.x & 0xFFFFu;
            pos[4*j+1] += v.y >> 16;  neg[4*j+1] += v.y & 0xFFFFu;
            pos[4*j+2] += v.z >> 16;  neg[4*j+2] += v.z & 0xFFFFu;
            pos[4*j+3] += v.w >> 16;  neg[4*j+3] += v.w & 0xFFFFu;
        }
    }

    double psum = 0.0;
#pragma unroll
    for (int i = 0; i < 8; ++i) psum += (double)pos[i];
    sA[tid] = psum;
    __syncthreads();

    // phase 2: Hillis-Steele inclusive scan over descending-chunk order
    double v = psum;
    for (int s = 1; s < 256; s <<= 1) {
        double add = (tid >= s) ? sA[tid - s] : 0.0;
        __syncthreads();
        v += add;
        sA[tid] = v;
        __syncthreads();
    }
    double CP = v - psum;   // positives strictly above this chunk

    const double T = RECALL_LO_C * Pd;

    // phase 3: walk chunk descending
    double S = 0.0;
#pragma unroll
    for (int i = 7; i >= 0; --i) {
        double p  = (double)pos[i];
        double ng = (double)neg[i];
        if (ng > 0.0) {
            double a = CP - T;
            double contrib;
            if (a >= 0.0) {
                contrib = a + 0.5 * p;
            } else {
                double ac = a + p;
                contrib = (ac > 0.0 && p > 0.0) ? (ac * ac) / (2.0 * p) : 0.0;
            }
            S += ng * contrib;
        }
        CP += p;
    }
    sB[tid] = S;
    __syncthreads();
    for (int s = 128; s > 0; s >>= 1) {
        if (tid < s) sB[tid] += sB[tid + s];
        __syncthreads();
    }

    if (tid == 0) {
        double Ng = (double)n - Pd;
        double pauc = 0.0;
        if (Pd > 0.0 && Ng > 0.0) pauc = sB[0] / (Pd * Ng);
        double avg = pauc / (2.0 * (1.0 - RECALL_LO_C));   // pauc / 0.1
        avg = fmin(fmax(avg, 0.0), 1.0);
        double ce = CE_total / (double)n;
        out[0] = (float)(0.5 * ce + 0.5 * (1.0 - avg * avg));
    }
}

extern "C" void kernel_launch(void* const* d_in, const int* in_sizes, int n_in,
                              void* d_out, int out_size, void* d_ws, size_t ws_size,
                              hipStream_t stream)
{
    const float* pred = (const float*)d_in[0];
    const int*   tgt  = (const int*)d_in[1];
    const int n = in_sizes[0];  // predictions is (N,1) -> N elements

    char* ws = (char*)d_ws;
    unsigned int* ghist    = (unsigned int*)ws;                        // 128 KB
    double*       ce_part  = (double*)(ws + NPART * HIST_BYTES);       // 16 KB
    unsigned int* pos_part = (unsigned int*)(ws + NPART * HIST_BYTES + GRID1 * 8); // 8 KB

    // only the histogram partials need zeroing; ce/pos slots are fully
    // overwritten by pass1 every launch
    hipMemsetAsync(d_ws, 0, NPART * HIST_BYTES, stream);

    pass1_kernel<<<GRID1, 256, 0, stream>>>(pred, tgt, ghist, ce_part, pos_part, n);
    pass2_kernel<<<1, 256, 0, stream>>>(ghist, ce_part, pos_part, (float*)d_out, n);
}

// Round 16
// 31.482 us; speedup vs baseline: 7.7220x; 1.1107x over previous
//
#include <hip/hip_runtime.h>

#define HIST_BINS 1024             // 2^10 bins: top-10 bits of monotonic key
#define HIST_BYTES (HIST_BINS * 4)
#define KEY_SHIFT 22
#define NPART 16                   // partial global histograms
#define RECALL_LO_C 0.95
#define GRID1 2048

// ---------------------------------------------------------------------------
// Pure-VALU softplus(-a) = log1p(exp(-a)), a >= 0. No trans pipe, no LDS.
// ---------------------------------------------------------------------------
__device__ __forceinline__ float softplus_neg(float a)
{
    const float LOG2E = 1.44269504088896341f;
    float t = fminf(a * LOG2E, 30.0f);
    float fi = rintf(t);
    float x = fi - t;                     // in [-0.5, 0.5]
    float p = 1.535336188319500e-4f;
    p = p * x + 1.339887440266574e-3f;
    p = p * x + 9.618437357674640e-3f;
    p = p * x + 5.550332471162809e-2f;
    p = p * x + 2.402264791363012e-1f;
    p = p * x + 6.931472028550421e-1f;
    float m = p * x + 1.0f;               // 2^(-r)
    int ii = (int)fi;
    float y = __uint_as_float(__float_as_uint(m) - ((unsigned int)ii << 23));
    float z1 = 1.0f + y;                  // (1, 2]
    bool red = z1 > 1.41421356f;
    float zr = red ? z1 * 0.5f : z1;
    float el = red ? 0.69314718056f : 0.0f;
    float w  = zr - 1.0f;
    float zz = w * w;
    float q = 7.0376836292e-2f;
    q = q * w - 1.1514610310e-1f;
    q = q * w + 1.1676998740e-1f;
    q = q * w - 1.2420140846e-1f;
    q = q * w + 1.4249322787e-1f;
    q = q * w - 1.6668057665e-1f;
    q = q * w + 2.0000714765e-1f;
    q = q * w - 2.4999993993e-1f;
    q = q * w + 3.3333331174e-1f;
    return w + (w * zz * q - 0.5f * zz) + el;
}

__device__ __forceinline__ void process4(
    float4 x, int4 t, float& ce, unsigned int& pc, unsigned int* lhist)
{
    float xs[4] = {x.x, x.y, x.z, x.w};
    int   ts[4] = {t.x, t.y, t.z, t.w};
#pragma unroll
    for (int c = 0; c < 4; ++c) {
        float xv = xs[c];
        ce += fmaxf(xv, 0.0f) - xv * (float)ts[c] + softplus_neg(fabsf(xv));
        pc += (unsigned int)ts[c];
        unsigned int u = __float_as_uint(xv);
        int          m = (int)u >> 31;
        unsigned int key = u ^ (0x80000000u | (unsigned int)m);
        atomicAdd(&lhist[key >> KEY_SHIFT], ts[c] ? 65536u : 1u);
    }
}

// ---------------------------------------------------------------------------
// Pass 1: stream + CE (pure-VALU softplus) + pos count + LDS 2^10-bin packed
// histogram. NO same-address global atomics anywhere (R15: that chain was the
// floor). Per-block ce/pos plain-store slots; NPART-partial rotated atomic
// flush (~2M total atomics, 1.8x less than R15). 2x float4 ILP: two adjacent
// float4+int4 pairs per iteration, exactly 2 iterations per thread.
// ---------------------------------------------------------------------------
__global__ __launch_bounds__(256) void pass1_kernel(
    const float* __restrict__ pred, const int* __restrict__ tgt,
    unsigned int* __restrict__ ghist, double* __restrict__ ce_part,
    unsigned int* __restrict__ pos_part, int n)
{
    __shared__ unsigned int lhist[HIST_BINS];   // 4 KB

    uint4* lh4 = (uint4*)lhist;
    for (int b = threadIdx.x; b < HIST_BINS / 4; b += 256)
        lh4[b] = make_uint4(0u, 0u, 0u, 0u);
    __syncthreads();

    float ce = 0.0f;
    unsigned int pc = 0;

    const int tid    = blockIdx.x * blockDim.x + threadIdx.x;
    const int stride = gridDim.x * blockDim.x;
    const int n8     = n >> 3;                 // float4 PAIRS

    const float4* p4 = (const float4*)pred;
    const int4*   t4 = (const int4*)tgt;

    for (int i = tid; i < n8; i += stride) {
        // issue all 4 loads before any processing (MLP)
        float4 x0 = p4[2 * i];
        float4 x1 = p4[2 * i + 1];
        int4   t0 = t4[2 * i];
        int4   t1 = t4[2 * i + 1];
        process4(x0, t0, ce, pc, lhist);
        process4(x1, t1, ce, pc, lhist);
    }
    // scalar tail for n % 8 (none for N = 8.4M)
    for (int i = (n8 << 3) + tid; i < n; i += stride) {
        float xv = pred[i];
        int   ti = tgt[i];
        ce += fmaxf(xv, 0.0f) - xv * (float)ti + softplus_neg(fabsf(xv));
        pc += (unsigned int)ti;
        unsigned int u = __float_as_uint(xv);
        int          m = (int)u >> 31;
        unsigned int key = u ^ (0x80000000u | (unsigned int)m);
        atomicAdd(&lhist[key >> KEY_SHIFT], ti ? 65536u : 1u);
    }

    // CE / pos-count: wave reduce -> LDS -> ONE PLAIN STORE per block
    for (int off = 32; off > 0; off >>= 1) {
        ce += __shfl_down(ce, off);
        pc += __shfl_down(pc, off);
    }
    __shared__ float        lce[4];
    __shared__ unsigned int lpc[4];
    if ((threadIdx.x & 63) == 0) {
        lce[threadIdx.x >> 6] = ce;
        lpc[threadIdx.x >> 6] = pc;
    }
    __syncthreads();
    if (threadIdx.x == 0) {
        ce_part[blockIdx.x]  = (double)(lce[0] + lce[1] + lce[2] + lce[3]);
        pos_part[blockIdx.x] = lpc[0] + lpc[1] + lpc[2] + lpc[3];
    }

    // flush LDS histogram into this block's partial (rotated start);
    // nq = 256 -> exactly one uint4 per thread
    const int nq  = HIST_BINS / 4;
    const int rot = (blockIdx.x * 16) & (nq - 1);
    unsigned int* gp = ghist + (blockIdx.x & (NPART - 1)) * HIST_BINS;
    {
        int b = ((int)threadIdx.x + rot) & (nq - 1);
        uint4 v = lh4[b];
        if (v.x) atomicAdd(&gp[4 * b + 0], v.x);
        if (v.y) atomicAdd(&gp[4 * b + 1], v.y);
        if (v.z) atomicAdd(&gp[4 * b + 2], v.z);
        if (v.w) atomicAdd(&gp[4 * b + 3], v.w);
    }
}

// ---------------------------------------------------------------------------
// Pass 2 (single block, 256 threads):
//   phase 0: reduce per-block ce/pos partials (plain reads)
//   phase 1: unpacked 4-bin chunk summed across NPART partials
//   phase 2: Hillis-Steele scan (descending-chunk positive prefix)
//   phase 3: bin-wise pAUC: contrib = ng * E_f[max(0,(CP-0.95P)+p*f)]
// pAUC = S/(P*Ng);  loss = 0.5*CE_mean + 0.5*(1 - clip(pAUC/0.1,0,1)^2)
// ---------------------------------------------------------------------------
__global__ __launch_bounds__(256) void pass2_kernel(
    const unsigned int* __restrict__ hist, const double* __restrict__ ce_part,
    const unsigned int* __restrict__ pos_part, float* __restrict__ out, int n)
{
    __shared__ double sA[256];
    __shared__ double sB[256];

    const int tid = threadIdx.x;

    // phase 0
    double ce_acc = 0.0, p_acc = 0.0;
    for (int i = tid; i < GRID1; i += 256) {
        ce_acc += ce_part[i];
        p_acc  += (double)pos_part[i];
    }
    sA[tid] = ce_acc;
    sB[tid] = p_acc;
    __syncthreads();
    for (int s = 128; s > 0; s >>= 1) {
        if (tid < s) { sA[tid] += sA[tid + s]; sB[tid] += sB[tid + s]; }
        __syncthreads();
    }
    const double CE_total = sA[0];
    const double Pd       = sB[0];
    __syncthreads();

    // phase 1: 4 bins per thread
    const int lo = HIST_BINS - (tid + 1) * 4;
    unsigned int pos[4] = {0,0,0,0};
    unsigned int neg[4] = {0,0,0,0};
    const uint4* h4 = (const uint4*)hist;
#pragma unroll
    for (int p = 0; p < NPART; ++p) {
        uint4 v = h4[p * (HIST_BINS / 4) + lo / 4];
        pos[0] += v.x >> 16;  neg[0] += v.x & 0xFFFFu;
        pos[1] += v.y >> 16;  neg[1] += v.y & 0xFFFFu;
        pos[2] += v.z >> 16;  neg[2] += v.z & 0xFFFFu;
        pos[3] += v.w >> 16;  neg[3] += v.w & 0xFFFFu;
    }

    double psum = (double)pos[0] + pos[1] + pos[2] + pos[3];
    sA[tid] = psum;
    __syncthreads();

    // phase 2
    double v = psum;
    for (int s = 1; s < 256; s <<= 1) {
        double add = (tid >= s) ? sA[tid - s] : 0.0;
        __syncthreads();
        v += add;
        sA[tid] = v;
        __syncthreads();
    }
    double CP = v - psum;

    const double T = RECALL_LO_C * Pd;

    // phase 3
    double S = 0.0;
#pragma unroll
    for (int i = 3; i >= 0; --i) {
        double p  = (double)pos[i];
        double ng = (double)neg[i];
        if (ng > 0.0) {
            double a = CP - T;
            double contrib;
            if (a >= 0.0) {
                contrib = a + 0.5 * p;
            } else {
                double ac = a + p;
                contrib = (ac > 0.0 && p > 0.0) ? (ac * ac) / (2.0 * p) : 0.0;
            }
            S += ng * contrib;
        }
        CP += p;
    }
    sB[tid] = S;
    __syncthreads();
    for (int s = 128; s > 0; s >>= 1) {
        if (tid < s) sB[tid] += sB[tid + s];
        __syncthreads();
    }

    if (tid == 0) {
        double Ng = (double)n - Pd;
        double pauc = 0.0;
        if (Pd > 0.0 && Ng > 0.0) pauc = sB[0] / (Pd * Ng);
        double avg = pauc / (2.0 * (1.0 - RECALL_LO_C));   // pauc / 0.1
        avg = fmin(fmax(avg, 0.0), 1.0);
        double ce = CE_total / (double)n;
        out[0] = (float)(0.5 * ce + 0.5 * (1.0 - avg * avg));
    }
}

extern "C" void kernel_launch(void* const* d_in, const int* in_sizes, int n_in,
                              void* d_out, int out_size, void* d_ws, size_t ws_size,
                              hipStream_t stream)
{
    const float* pred = (const float*)d_in[0];
    const int*   tgt  = (const int*)d_in[1];
    const int n = in_sizes[0];  // predictions is (N,1) -> N elements

    char* ws = (char*)d_ws;
    unsigned int* ghist    = (unsigned int*)ws;                        // 64 KB
    double*       ce_part  = (double*)(ws + NPART * HIST_BYTES);       // 16 KB
    unsigned int* pos_part = (unsigned int*)(ws + NPART * HIST_BYTES + GRID1 * 8); // 8 KB

    // only the histogram partials need zeroing
    hipMemsetAsync(d_ws, 0, NPART * HIST_BYTES, stream);

    pass1_kernel<<<GRID1, 256, 0, stream>>>(pred, tgt, ghist, ce_part, pos_part, n);
    pass2_kernel<<<1, 256, 0, stream>>>(ghist, ce_part, pos_part, (float*)d_out, n);
}

// Round 17
// 30.456 us; speedup vs baseline: 7.9821x; 1.0337x over previous
//
#include <hip/hip_runtime.h>

#define HIST_BINS 1024             // 2^10 bins: top-10 bits of monotonic key
#define HIST_BYTES (HIST_BINS * 4)
#define KEY_SHIFT 22
#define NPART 32                   // partial global histograms (chain depth 64)
#define RECALL_LO_C 0.95
#define GRID1 2048

// ---------------------------------------------------------------------------
// Pure-VALU softplus(-a) = log1p(exp(-a)), a >= 0. No trans pipe, no LDS.
// ---------------------------------------------------------------------------
__device__ __forceinline__ float softplus_neg(float a)
{
    const float LOG2E = 1.44269504088896341f;
    float t = fminf(a * LOG2E, 30.0f);
    float fi = rintf(t);
    float x = fi - t;                     // in [-0.5, 0.5]
    float p = 1.535336188319500e-4f;
    p = p * x + 1.339887440266574e-3f;
    p = p * x + 9.618437357674640e-3f;
    p = p * x + 5.550332471162809e-2f;
    p = p * x + 2.402264791363012e-1f;
    p = p * x + 6.931472028550421e-1f;
    float m = p * x + 1.0f;               // 2^(-r)
    int ii = (int)fi;
    float y = __uint_as_float(__float_as_uint(m) - ((unsigned int)ii << 23));
    float z1 = 1.0f + y;                  // (1, 2]
    bool red = z1 > 1.41421356f;
    float zr = red ? z1 * 0.5f : z1;
    float el = red ? 0.69314718056f : 0.0f;
    float w  = zr - 1.0f;
    float zz = w * w;
    float q = 7.0376836292e-2f;
    q = q * w - 1.1514610310e-1f;
    q = q * w + 1.1676998740e-1f;
    q = q * w - 1.2420140846e-1f;
    q = q * w + 1.4249322787e-1f;
    q = q * w - 1.6668057665e-1f;
    q = q * w + 2.0000714765e-1f;
    q = q * w - 2.4999993993e-1f;
    q = q * w + 3.3333331174e-1f;
    return w + (w * zz * q - 0.5f * zz) + el;
}

__device__ __forceinline__ void process4(
    float4 x, int4 t, float& ce, unsigned int& pc, unsigned int* lhist)
{
    float xs[4] = {x.x, x.y, x.z, x.w};
    int   ts[4] = {t.x, t.y, t.z, t.w};
#pragma unroll
    for (int c = 0; c < 4; ++c) {
        float xv = xs[c];
        ce += fmaxf(xv, 0.0f) - xv * (float)ts[c] + softplus_neg(fabsf(xv));
        pc += (unsigned int)ts[c];
        unsigned int u = __float_as_uint(xv);
        int          m = (int)u >> 31;
        unsigned int key = u ^ (0x80000000u | (unsigned int)m);
        atomicAdd(&lhist[key >> KEY_SHIFT], ts[c] ? 65536u : 1u);
    }
}

// ---------------------------------------------------------------------------
// Pass 1: stream + CE (pure-VALU softplus) + pos count + LDS 2^10-bin packed
// histogram. NO same-address global atomics (R15: that chain was the floor).
// Wave-contiguous 4x-unrolled loads: each wave owns one 256-float4 chunk
// (8192 waves x 256 = N/4 exactly), lane reads wstart + j*64 + lane ->
// 8 fully-coalesced 1KB loads in flight per thread.
// Per-block ce/pos plain-store slots; NPART=32 rotated atomic flush.
// ---------------------------------------------------------------------------
__global__ __launch_bounds__(256) void pass1_kernel(
    const float* __restrict__ pred, const int* __restrict__ tgt,
    unsigned int* __restrict__ ghist, double* __restrict__ ce_part,
    unsigned int* __restrict__ pos_part, int n)
{
    __shared__ unsigned int lhist[HIST_BINS];   // 4 KB

    uint4* lh4 = (uint4*)lhist;
    for (int b = threadIdx.x; b < HIST_BINS / 4; b += 256)
        lh4[b] = make_uint4(0u, 0u, 0u, 0u);
    __syncthreads();

    float ce = 0.0f;
    unsigned int pc = 0;

    const int tid      = blockIdx.x * blockDim.x + threadIdx.x;
    const int nthreads = gridDim.x * blockDim.x;
    const int lane     = threadIdx.x & 63;
    const int gwid     = tid >> 6;
    const int nwaves   = nthreads >> 6;
    const int n4       = n >> 2;

    const float4* p4 = (const float4*)pred;
    const int4*   t4 = (const int4*)tgt;

    // each wave owns one contiguous 256-float4 (4 KB) chunk
    for (int wstart = gwid * 256; wstart < n4; wstart += nwaves * 256) {
        if (wstart + 256 <= n4) {
            float4 x0 = p4[wstart + 0 * 64 + lane];
            float4 x1 = p4[wstart + 1 * 64 + lane];
            float4 x2 = p4[wstart + 2 * 64 + lane];
            float4 x3 = p4[wstart + 3 * 64 + lane];
            int4   t0 = t4[wstart + 0 * 64 + lane];
            int4   t1 = t4[wstart + 1 * 64 + lane];
            int4   t2 = t4[wstart + 2 * 64 + lane];
            int4   t3 = t4[wstart + 3 * 64 + lane];
            process4(x0, t0, ce, pc, lhist);
            process4(x1, t1, ce, pc, lhist);
            process4(x2, t2, ce, pc, lhist);
            process4(x3, t3, ce, pc, lhist);
        } else {
            for (int j = 0; j < 4; ++j) {
                int idx = wstart + j * 64 + lane;
                if (idx < n4) {
                    process4(p4[idx], t4[idx], ce, pc, lhist);
                }
            }
        }
    }
    // scalar tail for n % 4 (none for N = 8.4M)
    for (int i = (n4 << 2) + tid; i < n; i += nthreads) {
        float xv = pred[i];
        int   ti = tgt[i];
        ce += fmaxf(xv, 0.0f) - xv * (float)ti + softplus_neg(fabsf(xv));
        pc += (unsigned int)ti;
        unsigned int u = __float_as_uint(xv);
        int          m = (int)u >> 31;
        unsigned int key = u ^ (0x80000000u | (unsigned int)m);
        atomicAdd(&lhist[key >> KEY_SHIFT], ti ? 65536u : 1u);
    }

    // CE / pos-count: wave reduce -> LDS -> ONE PLAIN STORE per block
    for (int off = 32; off > 0; off >>= 1) {
        ce += __shfl_down(ce, off);
        pc += __shfl_down(pc, off);
    }
    __shared__ float        lce[4];
    __shared__ unsigned int lpc[4];
    if ((threadIdx.x & 63) == 0) {
        lce[threadIdx.x >> 6] = ce;
        lpc[threadIdx.x >> 6] = pc;
    }
    __syncthreads();
    if (threadIdx.x == 0) {
        ce_part[blockIdx.x]  = (double)(lce[0] + lce[1] + lce[2] + lce[3]);
        pos_part[blockIdx.x] = lpc[0] + lpc[1] + lpc[2] + lpc[3];
    }

    // flush LDS histogram into this block's partial (rotated start);
    // nq = 256 -> exactly one uint4 per thread
    const int nq  = HIST_BINS / 4;
    const int rot = (blockIdx.x * 16) & (nq - 1);
    unsigned int* gp = ghist + (blockIdx.x & (NPART - 1)) * HIST_BINS;
    {
        int b = ((int)threadIdx.x + rot) & (nq - 1);
        uint4 v = lh4[b];
        if (v.x) atomicAdd(&gp[4 * b + 0], v.x);
        if (v.y) atomicAdd(&gp[4 * b + 1], v.y);
        if (v.z) atomicAdd(&gp[4 * b + 2], v.z);
        if (v.w) atomicAdd(&gp[4 * b + 3], v.w);
    }
}

// ---------------------------------------------------------------------------
// Pass 2 (single block, 256 threads):
//   phase 0: reduce per-block ce/pos partials (plain reads)
//   phase 1: unpacked 4-bin chunk summed across NPART partials
//   phase 2: Hillis-Steele scan (descending-chunk positive prefix)
//   phase 3: bin-wise pAUC: contrib = ng * E_f[max(0,(CP-0.95P)+p*f)]
// pAUC = S/(P*Ng);  loss = 0.5*CE_mean + 0.5*(1 - clip(pAUC/0.1,0,1)^2)
// ---------------------------------------------------------------------------
__global__ __launch_bounds__(256) void pass2_kernel(
    const unsigned int* __restrict__ hist, const double* __restrict__ ce_part,
    const unsigned int* __restrict__ pos_part, float* __restrict__ out, int n)
{
    __shared__ double sA[256];
    __shared__ double sB[256];

    const int tid = threadIdx.x;

    // phase 0
    double ce_acc = 0.0, p_acc = 0.0;
    for (int i = tid; i < GRID1; i += 256) {
        ce_acc += ce_part[i];
        p_acc  += (double)pos_part[i];
    }
    sA[tid] = ce_acc;
    sB[tid] = p_acc;
    __syncthreads();
    for (int s = 128; s > 0; s >>= 1) {
        if (tid < s) { sA[tid] += sA[tid + s]; sB[tid] += sB[tid + s]; }
        __syncthreads();
    }
    const double CE_total = sA[0];
    const double Pd       = sB[0];
    __syncthreads();

    // phase 1: 4 bins per thread, summed across NPART partials
    const int lo = HIST_BINS - (tid + 1) * 4;
    unsigned int pos[4] = {0,0,0,0};
    unsigned int neg[4] = {0,0,0,0};
    const uint4* h4 = (const uint4*)hist;
#pragma unroll
    for (int p = 0; p < NPART; ++p) {
        uint4 v = h4[p * (HIST_BINS / 4) + lo / 4];
        pos[0] += v.x >> 16;  neg[0] += v.x & 0xFFFFu;
        pos[1] += v.y >> 16;  neg[1] += v.y & 0xFFFFu;
        pos[2] += v.z >> 16;  neg[2] += v.z & 0xFFFFu;
        pos[3] += v.w >> 16;  neg[3] += v.w & 0xFFFFu;
    }

    double psum = (double)pos[0] + pos[1] + pos[2] + pos[3];
    sA[tid] = psum;
    __syncthreads();

    // phase 2
    double v = psum;
    for (int s = 1; s < 256; s <<= 1) {
        double add = (tid >= s) ? sA[tid - s] : 0.0;
        __syncthreads();
        v += add;
        sA[tid] = v;
        __syncthreads();
    }
    double CP = v - psum;

    const double T = RECALL_LO_C * Pd;

    // phase 3
    double S = 0.0;
#pragma unroll
    for (int i = 3; i >= 0; --i) {
        double p  = (double)pos[i];
        double ng = (double)neg[i];
        if (ng > 0.0) {
            double a = CP - T;
            double contrib;
            if (a >= 0.0) {
                contrib = a + 0.5 * p;
            } else {
                double ac = a + p;
                contrib = (ac > 0.0 && p > 0.0) ? (ac * ac) / (2.0 * p) : 0.0;
            }
            S += ng * contrib;
        }
        CP += p;
    }
    sB[tid] = S;
    __syncthreads();
    for (int s = 128; s > 0; s >>= 1) {
        if (tid < s) sB[tid] += sB[tid + s];
        __syncthreads();
    }

    if (tid == 0) {
        double Ng = (double)n - Pd;
        double pauc = 0.0;
        if (Pd > 0.0 && Ng > 0.0) pauc = sB[0] / (Pd * Ng);
        double avg = pauc / (2.0 * (1.0 - RECALL_LO_C));   // pauc / 0.1
        avg = fmin(fmax(avg, 0.0), 1.0);
        double ce = CE_total / (double)n;
        out[0] = (float)(0.5 * ce + 0.5 * (1.0 - avg * avg));
    }
}

extern "C" void kernel_launch(void* const* d_in, const int* in_sizes, int n_in,
                              void* d_out, int out_size, void* d_ws, size_t ws_size,
                              hipStream_t stream)
{
    const float* pred = (const float*)d_in[0];
    const int*   tgt  = (const int*)d_in[1];
    const int n = in_sizes[0];  // predictions is (N,1) -> N elements

    char* ws = (char*)d_ws;
    unsigned int* ghist    = (unsigned int*)ws;                        // 128 KB
    double*       ce_part  = (double*)(ws + NPART * HIST_BYTES);       // 16 KB
    unsigned int* pos_part = (unsigned int*)(ws + NPART * HIST_BYTES + GRID1 * 8); // 8 KB

    // only the histogram partials need zeroing
    hipMemsetAsync(d_ws, 0, NPART * HIST_BYTES, stream);

    pass1_kernel<<<GRID1, 256, 0, stream>>>(pred, tgt, ghist, ce_part, pos_part, n);
    pass2_kernel<<<1, 256, 0, stream>>>(ghist, ce_part, pos_part, (float*)d_out, n);
}

// Round 19
// 30.163 us; speedup vs baseline: 8.0597x; 1.0097x over previous
//
#include <hip/hip_runtime.h>

#define HIST_BINS 1024             // 2^10 bins: top-10 bits of monotonic key
#define HIST_BYTES (HIST_BINS * 4)
#define KEY_SHIFT 22
#define NPART 32                   // partial global histograms (chain depth 64)
#define RECALL_LO_C 0.95
#define GRID1 2048

typedef float fx4 __attribute__((ext_vector_type(4)));
typedef int   ix4 __attribute__((ext_vector_type(4)));

// ---------------------------------------------------------------------------
// Pure-VALU softplus(-a) = log1p(exp(-a)), a >= 0. No trans pipe, no LDS.
// ---------------------------------------------------------------------------
__device__ __forceinline__ float softplus_neg(float a)
{
    const float LOG2E = 1.44269504088896341f;
    float t = fminf(a * LOG2E, 30.0f);
    float fi = rintf(t);
    float x = fi - t;                     // in [-0.5, 0.5]
    float p = 1.535336188319500e-4f;
    p = p * x + 1.339887440266574e-3f;
    p = p * x + 9.618437357674640e-3f;
    p = p * x + 5.550332471162809e-2f;
    p = p * x + 2.402264791363012e-1f;
    p = p * x + 6.931472028550421e-1f;
    float m = p * x + 1.0f;               // 2^(-r)
    int ii = (int)fi;
    float y = __uint_as_float(__float_as_uint(m) - ((unsigned int)ii << 23));
    float z1 = 1.0f + y;                  // (1, 2]
    bool red = z1 > 1.41421356f;
    float zr = red ? z1 * 0.5f : z1;
    float el = red ? 0.69314718056f : 0.0f;
    float w  = zr - 1.0f;
    float zz = w * w;
    float q = 7.0376836292e-2f;
    q = q * w - 1.1514610310e-1f;
    q = q * w + 1.1676998740e-1f;
    q = q * w - 1.2420140846e-1f;
    q = q * w + 1.4249322787e-1f;
    q = q * w - 1.6668057665e-1f;
    q = q * w + 2.0000714765e-1f;
    q = q * w - 2.4999993993e-1f;
    q = q * w + 3.3333331174e-1f;
    return w + (w * zz * q - 0.5f * zz) + el;
}

__device__ __forceinline__ void process4(
    fx4 x, ix4 t, float& ce, unsigned int& pc, unsigned int* lhist)
{
#pragma unroll
    for (int c = 0; c < 4; ++c) {
        float xv = x[c];
        int   tv = t[c];
        ce += fmaxf(xv, 0.0f) - xv * (float)tv + softplus_neg(fabsf(xv));
        pc += (unsigned int)tv;
        unsigned int u = __float_as_uint(xv);
        int          m = (int)u >> 31;
        unsigned int key = u ^ (0x80000000u | (unsigned int)m);
        atomicAdd(&lhist[key >> KEY_SHIFT], tv ? 65536u : 1u);
    }
}

// ---------------------------------------------------------------------------
// Pass 1: stream + CE (pure-VALU softplus) + pos count + LDS 2^10-bin packed
// histogram. NO same-address global atomics (R15: that chain was the floor).
// Wave-contiguous 8x-unrolled NONTEMPORAL loads: each wave owns one
// 512-float4 (8 KB) chunk — 8192 waves x 512 = N/4 exactly, so one chunk per
// wave; 16 coalesced 1KB loads in flight per thread.
// Per-block ce/pos plain-store slots; NPART=32 rotated atomic flush.
// ---------------------------------------------------------------------------
__global__ __launch_bounds__(256) void pass1_kernel(
    const float* __restrict__ pred, const int* __restrict__ tgt,
    unsigned int* __restrict__ ghist, double* __restrict__ ce_part,
    unsigned int* __restrict__ pos_part, int n)
{
    __shared__ unsigned int lhist[HIST_BINS];   // 4 KB

    uint4* lh4 = (uint4*)lhist;
    for (int b = threadIdx.x; b < HIST_BINS / 4; b += 256)
        lh4[b] = make_uint4(0u, 0u, 0u, 0u);
    __syncthreads();

    float ce = 0.0f;
    unsigned int pc = 0;

    const int tid      = blockIdx.x * blockDim.x + threadIdx.x;
    const int nthreads = gridDim.x * blockDim.x;
    const int lane     = threadIdx.x & 63;
    const int gwid     = tid >> 6;
    const int nwaves   = nthreads >> 6;
    const int n4       = n >> 2;

    const fx4* p4 = (const fx4*)pred;
    const ix4* t4 = (const ix4*)tgt;

    // each wave owns one contiguous 512-float4 (8 KB) chunk
    for (int wstart = gwid * 512; wstart < n4; wstart += nwaves * 512) {
        if (wstart + 512 <= n4) {
            fx4 x[8];
            ix4 t[8];
#pragma unroll
            for (int j = 0; j < 8; ++j)
                x[j] = __builtin_nontemporal_load(&p4[wstart + j * 64 + lane]);
#pragma unroll
            for (int j = 0; j < 8; ++j)
                t[j] = __builtin_nontemporal_load(&t4[wstart + j * 64 + lane]);
#pragma unroll
            for (int j = 0; j < 8; ++j)
                process4(x[j], t[j], ce, pc, lhist);
        } else {
            for (int j = 0; j < 8; ++j) {
                int idx = wstart + j * 64 + lane;
                if (idx < n4) process4(p4[idx], t4[idx], ce, pc, lhist);
            }
        }
    }
    // scalar tail for n % 4 (none for N = 8.4M)
    for (int i = (n4 << 2) + tid; i < n; i += nthreads) {
        float xv = pred[i];
        int   ti = tgt[i];
        ce += fmaxf(xv, 0.0f) - xv * (float)ti + softplus_neg(fabsf(xv));
        pc += (unsigned int)ti;
        unsigned int u = __float_as_uint(xv);
        int          m = (int)u >> 31;
        unsigned int key = u ^ (0x80000000u | (unsigned int)m);
        atomicAdd(&lhist[key >> KEY_SHIFT], ti ? 65536u : 1u);
    }

    // CE / pos-count: wave reduce -> LDS -> ONE PLAIN STORE per block
    for (int off = 32; off > 0; off >>= 1) {
        ce += __shfl_down(ce, off);
        pc += __shfl_down(pc, off);
    }
    __shared__ float        lce[4];
    __shared__ unsigned int lpc[4];
    if ((threadIdx.x & 63) == 0) {
        lce[threadIdx.x >> 6] = ce;
        lpc[threadIdx.x >> 6] = pc;
    }
    __syncthreads();
    if (threadIdx.x == 0) {
        ce_part[blockIdx.x]  = (double)(lce[0] + lce[1] + lce[2] + lce[3]);
        pos_part[blockIdx.x] = lpc[0] + lpc[1] + lpc[2] + lpc[3];
    }

    // flush LDS histogram into this block's partial (rotated start);
    // nq = 256 -> exactly one uint4 per thread
    const int nq  = HIST_BINS / 4;
    const int rot = (blockIdx.x * 16) & (nq - 1);
    unsigned int* gp = ghist + (blockIdx.x & (NPART - 1)) * HIST_BINS;
    {
        int b = ((int)threadIdx.x + rot) & (nq - 1);
        uint4 v = lh4[b];
        if (v.x) atomicAdd(&gp[4 * b + 0], v.x);
        if (v.y) atomicAdd(&gp[4 * b + 1], v.y);
        if (v.z) atomicAdd(&gp[4 * b + 2], v.z);
        if (v.w) atomicAdd(&gp[4 * b + 3], v.w);
    }
}

// ---------------------------------------------------------------------------
// Pass 2 (single block, 256 threads):
//   phase 0: reduce per-block ce/pos partials (plain reads)
//   phase 1: unpacked 4-bin chunk summed across NPART partials
//   phase 2: Hillis-Steele scan (descending-chunk positive prefix)
//   phase 3: bin-wise pAUC: contrib = ng * E_f[max(0,(CP-0.95P)+p*f)]
// pAUC = S/(P*Ng);  loss = 0.5*CE_mean + 0.5*(1 - clip(pAUC/0.1,0,1)^2)
// ---------------------------------------------------------------------------
__global__ __launch_bounds__(256) void pass2_kernel(
    const unsigned int* __restrict__ hist, const double* __restrict__ ce_part,
    const unsigned int* __restrict__ pos_part, float* __restrict__ out, int n)
{
    __shared__ double sA[256];
    __shared__ double sB[256];

    const int tid = threadIdx.x;

    // phase 0
    double ce_acc = 0.0, p_acc = 0.0;
    for (int i = tid; i < GRID1; i += 256) {
        ce_acc += ce_part[i];
        p_acc  += (double)pos_part[i];
    }
    sA[tid] = ce_acc;
    sB[tid] = p_acc;
    __syncthreads();
    for (int s = 128; s > 0; s >>= 1) {
        if (tid < s) { sA[tid] += sA[tid + s]; sB[tid] += sB[tid + s]; }
        __syncthreads();
    }
    const double CE_total = sA[0];
    const double Pd       = sB[0];
    __syncthreads();

    // phase 1: 4 bins per thread, summed across NPART partials
    const int lo = HIST_BINS - (tid + 1) * 4;
    unsigned int pos[4] = {0,0,0,0};
    unsigned int neg[4] = {0,0,0,0};
    const uint4* h4 = (const uint4*)hist;
#pragma unroll
    for (int p = 0; p < NPART; ++p) {
        uint4 v = h4[p * (HIST_BINS / 4) + lo / 4];
        pos[0] += v.x >> 16;  neg[0] += v.x & 0xFFFFu;
        pos[1] += v.y >> 16;  neg[1] += v.y & 0xFFFFu;
        pos[2] += v.z >> 16;  neg[2] += v.z & 0xFFFFu;
        pos[3] += v.w >> 16;  neg[3] += v.w & 0xFFFFu;
    }

    double psum = (double)pos[0] + pos[1] + pos[2] + pos[3];
    sA[tid] = psum;
    __syncthreads();

    // phase 2
    double v = psum;
    for (int s = 1; s < 256; s <<= 1) {
        double add = (tid >= s) ? sA[tid - s] : 0.0;
        __syncthreads();
        v += add;
        sA[tid] = v;
        __syncthreads();
    }
    double CP = v - psum;

    const double T = RECALL_LO_C * Pd;

    // phase 3
    double S = 0.0;
#pragma unroll
    for (int i = 3; i >= 0; --i) {
        double p  = (double)pos[i];
        double ng = (double)neg[i];
        if (ng > 0.0) {
            double a = CP - T;
            double contrib;
            if (a >= 0.0) {
                contrib = a + 0.5 * p;
            } else {
                double ac = a + p;
                contrib = (ac > 0.0 && p > 0.0) ? (ac * ac) / (2.0 * p) : 0.0;
            }
            S += ng * contrib;
        }
        CP += p;
    }
    sB[tid] = S;
    __syncthreads();
    for (int s = 128; s > 0; s >>= 1) {
        if (tid < s) sB[tid] += sB[tid + s];
        __syncthreads();
    }

    if (tid == 0) {
        double Ng = (double)n - Pd;
        double pauc = 0.0;
        if (Pd > 0.0 && Ng > 0.0) pauc = sB[0] / (Pd * Ng);
        double avg = pauc / (2.0 * (1.0 - RECALL_LO_C));   // pauc / 0.1
        avg = fmin(fmax(avg, 0.0), 1.0);
        double ce = CE_total / (double)n;
        out[0] = (float)(0.5 * ce + 0.5 * (1.0 - avg * avg));
    }
}

extern "C" void kernel_launch(void* const* d_in, const int* in_sizes, int n_in,
                              void* d_out, int out_size, void* d_ws, size_t ws_size,
                              hipStream_t stream)
{
    const float* pred = (const float*)d_in[0];
    const int*   tgt  = (const int*)d_in[1];
    const int n = in_sizes[0];  // predictions is (N,1) -> N elements

    char* ws = (char*)d_ws;
    unsigned int* ghist    = (unsigned int*)ws;                        // 128 KB
    double*       ce_part  = (double*)(ws + NPART * HIST_BYTES);       // 16 KB
    unsigned int* pos_part = (unsigned int*)(ws + NPART * HIST_BYTES + GRID1 * 8); // 8 KB

    // only the histogram partials need zeroing
    (void)hipMemsetAsync(d_ws, 0, NPART * HIST_BYTES, stream);

    pass1_kernel<<<GRID1, 256, 0, stream>>>(pred, tgt, ghist, ce_part, pos_part, n);
    pass2_kernel<<<1, 256, 0, stream>>>(ghist, ce_part, pos_part, (float*)d_out, n);
}